// Round 17
// baseline (1809.742 us; speedup 1.0000x reference)
//
#include <hip/hip_runtime.h>
#include <stdint.h>

typedef unsigned short u16;
typedef unsigned char u8;
typedef unsigned int u32;
typedef unsigned long long u64;

using h8f  = __attribute__((ext_vector_type(8))) _Float16;  // 8 f16 (one MFMA frag)
using f4_t = __attribute__((ext_vector_type(4))) float;

#define MFMAH(a,b,c)  __builtin_amdgcn_mfma_f32_16x16x32_f16((a),(b),(c),0,0,0)

#define LO_SCALE 4096.0f
#define LO_INV   0.000244140625f   // 1/4096

__device__ __forceinline__ float sigm(float x) {
  return __builtin_amdgcn_rcpf(1.f + __expf(-x));
}
__device__ __forceinline__ float tanh_f(float x) {
  x = fminf(30.f, fmaxf(-30.f, x));
  float e = __expf(-2.f * x);
  return (1.f - e) * __builtin_amdgcn_rcpf(1.f + e);
}
__device__ __forceinline__ u16 f2h_bits(float f) {   // RNE f32->f16 bits
  _Float16 h = (_Float16)f;
  union { _Float16 h; u16 u; } v; v.h = h; return v.u;
}
__device__ __forceinline__ float h2f(u16 u) {
  union { _Float16 h; u16 u; } v; v.u = u; return (float)v.h;
}
// v_cvt_pkrtz_f16_f32: 2 f32 -> 2 f16 (RTZ; paired with exact lo channel)
__device__ __forceinline__ u32 pkrtz(float a, float b) {
  union { __attribute__((ext_vector_type(2))) __fp16 h; u32 u; } v;
  v.h = __builtin_amdgcn_cvt_pkrtz(a, b);
  return v.u;
}

// ---------------- prep kernels ----------------

__global__ void k_gemm128(const float* __restrict__ A, const float* __restrict__ B,
                          float* __restrict__ C) {
  int g = blockIdx.x * 256 + threadIdx.x;
  int row = g >> 5;
  int c0 = (g & 31) << 2;
  f4_t acc = {0.f, 0.f, 0.f, 0.f};
  for (int k = 0; k < 128; ++k) {
    float a = A[row * 128 + k];
    acc += a * *(const f4_t*)&B[k * 128 + c0];
  }
  *(f4_t*)&C[row * 128 + c0] = acc;
}

__global__ void k_wbig(const float* __restrict__ fc_W, const float* __restrict__ B2,
                       const float* __restrict__ B3, float* __restrict__ WB) {
  int g = blockIdx.x * 256 + threadIdx.x;
  int row = g / 96;
  int j0 = (g % 96) * 4;
  if (j0 < 128) {
    *(f4_t*)&WB[row * 384 + j0] = *(const f4_t*)&fc_W[row * 128 + j0];
  } else {
    const float* Bm = (j0 < 256) ? B2 : B3;
    int jj = j0 & 127;
    f4_t acc = {0.f, 0.f, 0.f, 0.f};
    for (int n = 0; n < 128; ++n)
      acc += fc_W[row * 128 + n] * *(const f4_t*)&Bm[n * 128 + jj];
    *(f4_t*)&WB[row * 384 + j0] = acc;
  }
}

__global__ void k_bbig(const float* __restrict__ fc_b, const float* __restrict__ fc2_b,
                       const float* __restrict__ B2, const float* __restrict__ B3,
                       const float* __restrict__ Wq2, const float* __restrict__ Wk3,
                       float* __restrict__ bb) {
  int j = blockIdx.x * 256 + threadIdx.x;
  if (j >= 384) return;
  if (j < 128) { bb[j] = fc_b[j]; return; }
  const float* Bm = (j < 256) ? B2 : B3;
  const float* Wm = (j < 256) ? Wq2 : Wk3;
  int jj = j & 127;
  float acc = 0.f;
  for (int n = 0; n < 128; ++n)
    acc += fc_b[n] * Bm[n * 128 + jj] + fc2_b[n] * Wm[n * 128 + jj];
  bb[j] = acc;
}

__global__ void k_skdf(const float* __restrict__ skill_emb, const float* __restrict__ diff_emb,
                       const float* __restrict__ WB, const float* __restrict__ bb,
                       float* __restrict__ SK, float* __restrict__ DF) {
  int g = blockIdx.x * 256 + threadIdx.x;
  int row = g / 96, j0 = (g % 96) * 4;
  if (blockIdx.y == 0) {
    if (row >= 1002) return;
    f4_t acc = {0.f, 0.f, 0.f, 0.f};
    for (int d = 0; d < 128; ++d)
      acc += skill_emb[row * 128 + d] * *(const f4_t*)&WB[d * 384 + j0];
    *(f4_t*)&SK[row * 384 + j0] = acc;
  } else {
    if (row >= 102) return;
    f4_t acc = *(const f4_t*)&bb[j0];
    for (int d = 0; d < 128; ++d)
      acc += diff_emb[row * 128 + d] * *(const f4_t*)&WB[(128 + d) * 384 + j0];
    *(f4_t*)&DF[row * 384 + j0] = acc;
  }
}

__global__ void k_tv(const float* __restrict__ hints_emb, const float* __restrict__ Wv2,
                     const float* __restrict__ answer_emb, const float* __restrict__ Wv3,
                     float* __restrict__ Tv2, float* __restrict__ Tv3) {
  int g = blockIdx.x * 256 + threadIdx.x;
  if (g < 384) {
    int i = g >> 5, j0 = (g & 31) << 2;
    f4_t acc = {0.f, 0.f, 0.f, 0.f};
    for (int d = 0; d < 128; ++d)
      acc += hints_emb[i * 128 + d] * *(const f4_t*)&Wv2[d * 128 + j0];
    *(f4_t*)&Tv2[i * 128 + j0] = acc;
  } else if (g < 480) {
    int g2 = g - 384;
    int i = g2 >> 5, j0 = (g2 & 31) << 2;
    f4_t acc = {0.f, 0.f, 0.f, 0.f};
    for (int d = 0; d < 128; ++d)
      acc += answer_emb[i * 128 + d] * *(const f4_t*)&Wv3[d * 128 + j0];
    *(f4_t*)&Tv3[i * 128 + j0] = acc;
  }
}

// Pack in-loop weights. 8-wave layout: wave w (0..7) owns cols [16w,16w+16).
// frag flat index f = ((m*4+kk)*8 + w)*64 + lane ; 8 u16/frag.
// whi: f16 hi. wlo: f16 of ((w - f16(w)) * 4096)  (eff weight prec 2^-24).
struct P8 { const float* p[8]; };
__global__ void k_pack(P8 s, u16* __restrict__ whi, u16* __restrict__ wlo) {
  int g = blockIdx.x * 256 + threadIdx.x;   // 128*256 = 32768
  bool lo = (g >= 16384);
  int gg = g & 16383;
  int m = gg >> 11;
  int r = gg & 2047;
  int kk = r >> 9, w = (r >> 6) & 7, l = r & 63;
  const float* src = s.p[m];
  int col = w * 16 + (l & 15);
  int kbase = kk * 32 + ((l >> 4) << 3);
  u16 o[8];
  #pragma unroll
  for (int e = 0; e < 8; ++e) {
    float v = src[(kbase + e) * 128 + col];
    if (!lo) o[e] = f2h_bits(v);
    else     o[e] = f2h_bits((v - (float)((_Float16)v)) * LO_SCALE);
  }
  uint4 u;
  u.x = o[0] | ((u32)o[1] << 16); u.y = o[2] | ((u32)o[3] << 16);
  u.z = o[4] | ((u32)o[5] << 16); u.w = o[6] | ((u32)o[7] << 16);
  *(uint4*)((lo ? wlo : whi) + gg * 8) = u;
}

// ---------------- main recurrent kernel ----------------
// 32 blocks x 512 threads (8 waves, 2 waves/SIMD). Block owns 16 batch rows;
// wave w owns feature cols [16w,16w+16). WH f16-hi register-resident (128
// regs); WL f16 (res*4096) STREAMED from L2 each stage (16 b128/stage),
// consumed against the act-HI fragments already in registers -> no fp8 act
// copies needed. Acts: f16 hi + f16 lo in LDS (eff 2^-22; mandatory).
// Per wave/step: 96 f16 MFMA, 32 ds_read_b128, 8 LDS writes, 2 barriers.

#define RSTRIDE 136   // u16 stride (272 B)

__launch_bounds__(512, 2)
__global__ void k_main(const int* __restrict__ skill, const int* __restrict__ answer,
                       const int* __restrict__ diff, const int* __restrict__ hints,
                       const float* __restrict__ SK, const float* __restrict__ DF,
                       const float* __restrict__ Tv2, const float* __restrict__ Tv3,
                       const u16* __restrict__ whi, const u16* __restrict__ wlo,
                       const float* __restrict__ b11p, const float* __restrict__ b12p,
                       const float* __restrict__ b21p, const float* __restrict__ b22p,
                       float* __restrict__ out) {
  __shared__ u16 sh_h[16 * RSTRIDE], sh_hl[16 * RSTRIDE];
  __shared__ u16 sh_c[16 * RSTRIDE], sh_cl[16 * RSTRIDE];
  __shared__ u16 sh_o[16 * RSTRIDE], sh_ol[16 * RSTRIDE];
  __shared__ u16 sh_o3[16 * RSTRIDE], sh_o3l[16 * RSTRIDE];
  __shared__ float sh_red[128];

  const int tid = threadIdx.x;
  const int w = tid >> 6, lane = tid & 63;
  const int row = lane & 15;
  const int fgrp = lane >> 4;
  const int f0 = w * 16 + fgrp * 4;
  const int row_g = blockIdx.x * 16 + row;
  const int r200 = row_g * 200;

  // -------- persistent weights (hi f16; lo f16 streamed) --------
  h8f WH[8][4];
  #pragma unroll
  for (int m = 0; m < 8; ++m)
    #pragma unroll
    for (int kk = 0; kk < 4; ++kk)
      WH[m][kk] = *(const h8f*)&whi[(size_t)(((m * 4 + kk) * 8 + w) * 64 + lane) * 8];
  const u16* wlp = wlo + (size_t)(w * 64 + lane) * 8;   // + (m*4+kk)*512*8

  // LDS init (h,c hi/lo = 0)
  for (int i = tid; i < 16 * RSTRIDE / 2; i += 512) {
    ((u32*)sh_h)[i] = 0u; ((u32*)sh_c)[i] = 0u;
    ((u32*)sh_hl)[i] = 0u; ((u32*)sh_cl)[i] = 0u;
  }
  if (tid < 16) out[(blockIdx.x * 16 + tid) * 200 + 199] = 0.f;  // y[:,199]=0

  f4_t cst = {0.f, 0.f, 0.f, 0.f};

  int is_cur = skill[r200], id_cur = diff[r200];
  int ih_cur = hints[r200], ia_cur = answer[r200];

  const float inv = 0.088388347648318447f;  // 1/sqrt(128)
  const int rbase = row * RSTRIDE;
  const int widx = rbase + f0;
  int roff[4];
  #pragma unroll
  for (int kk = 0; kk < 4; ++kk) roff[kk] = rbase + kk * 32 + fgrp * 8;

  __syncthreads();

  for (int t = 0; t < 199; ++t) {
    // ---- S1 top: stream stage-1 WL (L2) + table loads + next idx ----
    h8f wls[4][4];
    #pragma unroll
    for (int m = 0; m < 4; ++m)
      #pragma unroll
      for (int kk = 0; kk < 4; ++kk)
        wls[m][kk] = *(const h8f*)(wlp + (size_t)((m * 4 + kk) * 512) * 8);
    f4_t v2  = *(const f4_t*)&Tv2[ih_cur * 128 + f0];
    f4_t v3  = *(const f4_t*)&Tv3[ia_cur * 128 + f0];
    f4_t q2b = *(const f4_t*)&SK[is_cur * 384 + 128 + f0]
             + *(const f4_t*)&DF[id_cur * 384 + 128 + f0];
    f4_t q3b = *(const f4_t*)&SK[is_cur * 384 + 256 + f0]
             + *(const f4_t*)&DF[id_cur * 384 + 256 + f0];
    int n_s = skill[r200 + t + 1];
    int n_d = diff[r200 + t + 1];
    int n_h = hints[r200 + t + 1];
    int n_a = answer[r200 + t + 1];

    // ---- stage 1 MFMAs: main (hi+lo acts) + lo-weight x act-hi ----
    f4_t q2 = {0.f,0.f,0.f,0.f}, q3 = {0.f,0.f,0.f,0.f};
    f4_t k3 = {0.f,0.f,0.f,0.f}, k2 = {0.f,0.f,0.f,0.f};
    f4_t lq2 = {0.f,0.f,0.f,0.f}, lq3 = {0.f,0.f,0.f,0.f};
    f4_t lk3 = {0.f,0.f,0.f,0.f}, lk2 = {0.f,0.f,0.f,0.f};
    #pragma unroll
    for (int kk = 0; kk < 4; ++kk) {
      h8f hh = *(const h8f*)&sh_h[roff[kk]];
      h8f hl = *(const h8f*)&sh_hl[roff[kk]];
      h8f ch = *(const h8f*)&sh_c[roff[kk]];
      h8f cl = *(const h8f*)&sh_cl[roff[kk]];
      q2 = MFMAH(WH[0][kk], hh, q2); q2 = MFMAH(WH[0][kk], hl, q2);
      q3 = MFMAH(WH[1][kk], hh, q3); q3 = MFMAH(WH[1][kk], hl, q3);
      k3 = MFMAH(WH[2][kk], hh, k3); k3 = MFMAH(WH[2][kk], hl, k3);
      k2 = MFMAH(WH[3][kk], ch, k2); k2 = MFMAH(WH[3][kk], cl, k2);
      lq2 = MFMAH(wls[0][kk], hh, lq2);
      lq3 = MFMAH(wls[1][kk], hh, lq3);
      lk3 = MFMAH(wls[2][kk], hh, lk3);
      lk2 = MFMAH(wls[3][kk], ch, lk2);
    }

    // ---- E1: gates + write o/o3 (f16 hi+lo) ----
    {
      float ov[4], o3v[4];
      #pragma unroll
      for (int r = 0; r < 4; ++r) {
        float q2v = (q2[r] + lq2[r] * LO_INV) + q2b[r];
        float q3v = (q3[r] + lq3[r] * LO_INV) + q3b[r];
        float k2v = k2[r] + lk2[r] * LO_INV;
        float k3v = k3[r] + lk3[r] * LO_INV;
        ov[r]  = v2[r] * sigm(q2v * k2v * inv);
        o3v[r] = v3[r] * sigm(q3v * k3v * inv);
      }
      uint2 ph; ph.x = pkrtz(ov[0], ov[1]); ph.y = pkrtz(ov[2], ov[3]);
      *(uint2*)&sh_o[widx] = ph;
      uint2 pl;
      pl.x = pkrtz(ov[0] - h2f((u16)ph.x), ov[1] - h2f((u16)(ph.x >> 16)));
      pl.y = pkrtz(ov[2] - h2f((u16)ph.y), ov[3] - h2f((u16)(ph.y >> 16)));
      *(uint2*)&sh_ol[widx] = pl;
      uint2 p3; p3.x = pkrtz(o3v[0], o3v[1]); p3.y = pkrtz(o3v[2], o3v[3]);
      *(uint2*)&sh_o3[widx] = p3;
      uint2 p3l;
      p3l.x = pkrtz(o3v[0] - h2f((u16)p3.x), o3v[1] - h2f((u16)(p3.x >> 16)));
      p3l.y = pkrtz(o3v[2] - h2f((u16)p3.y), o3v[3] - h2f((u16)(p3.y >> 16)));
      *(uint2*)&sh_o3l[widx] = p3l;
    }
    __syncthreads();

    // ---- S2 top: stream stage-2 WL + xn tables + biases ----
    h8f wls2[4][4];
    #pragma unroll
    for (int m = 0; m < 4; ++m)
      #pragma unroll
      for (int kk = 0; kk < 4; ++kk)
        wls2[m][kk] = *(const h8f*)(wlp + (size_t)(((m + 4) * 4 + kk) * 512) * 8);
    f4_t xn = *(const f4_t*)&SK[n_s * 384 + f0] + *(const f4_t*)&DF[n_d * 384 + f0];
    f4_t b11 = *(const f4_t*)&b11p[f0];
    f4_t b12 = *(const f4_t*)&b12p[f0];
    f4_t b21 = *(const f4_t*)&b21p[f0];
    f4_t b22 = *(const f4_t*)&b22p[f0];

    // ---- stage 2 MFMAs ----
    f4_t a11 = {0.f,0.f,0.f,0.f}, a12 = {0.f,0.f,0.f,0.f};
    f4_t a21 = {0.f,0.f,0.f,0.f}, a22 = {0.f,0.f,0.f,0.f};
    f4_t l11 = {0.f,0.f,0.f,0.f}, l12 = {0.f,0.f,0.f,0.f};
    f4_t l21 = {0.f,0.f,0.f,0.f}, l22 = {0.f,0.f,0.f,0.f};
    #pragma unroll
    for (int kk = 0; kk < 4; ++kk) {
      h8f of   = *(const h8f*)&sh_o[roff[kk]];
      h8f olf  = *(const h8f*)&sh_ol[roff[kk]];
      h8f o3f  = *(const h8f*)&sh_o3[roff[kk]];
      h8f o3lf = *(const h8f*)&sh_o3l[roff[kk]];
      a11 = MFMAH(WH[4][kk], of, a11);  a11 = MFMAH(WH[4][kk], olf, a11);
      a12 = MFMAH(WH[5][kk], of, a12);  a12 = MFMAH(WH[5][kk], olf, a12);
      a21 = MFMAH(WH[6][kk], o3f, a21); a21 = MFMAH(WH[6][kk], o3lf, a21);
      a22 = MFMAH(WH[7][kk], o3f, a22); a22 = MFMAH(WH[7][kk], o3lf, a22);
      l11 = MFMAH(wls2[0][kk], of, l11);
      l12 = MFMAH(wls2[1][kk], of, l12);
      l21 = MFMAH(wls2[2][kk], o3f, l21);
      l22 = MFMAH(wls2[3][kk], o3f, l22);
    }

    // ---- E2: state update + y partial + write h,c (f16 hi+lo) ----
    float part = 0.f;
    f4_t hv;
    #pragma unroll
    for (int r = 0; r < 4; ++r) {
      float v11 = (a11[r] + l11[r] * LO_INV) + b11[r];
      float v12 = (a12[r] + l12[r] * LO_INV) + b12[r];
      float v21 = (a21[r] + l21[r] * LO_INV) + b21[r];
      float v22 = (a22[r] + l22[r] * LO_INV) + b22[r];
      float g = tanh_f(v11) * sigm(v12);
      cst[r] += g;
      float hh = tanh_f(v21) * sigm(v22) + cst[r];
      hv[r] = hh;
      part += xn[r] * hh;
    }
    part += __shfl_xor(part, 16);
    part += __shfl_xor(part, 32);
    if (lane < 16) sh_red[lane * 8 + w] = part;

    {
      uint2 ph; ph.x = pkrtz(hv[0], hv[1]); ph.y = pkrtz(hv[2], hv[3]);
      *(uint2*)&sh_h[widx] = ph;
      uint2 pl;
      pl.x = pkrtz(hv[0] - h2f((u16)ph.x), hv[1] - h2f((u16)(ph.x >> 16)));
      pl.y = pkrtz(hv[2] - h2f((u16)ph.y), hv[3] - h2f((u16)(ph.y >> 16)));
      *(uint2*)&sh_hl[widx] = pl;
      uint2 pc; pc.x = pkrtz(cst[0], cst[1]); pc.y = pkrtz(cst[2], cst[3]);
      *(uint2*)&sh_c[widx] = pc;
      uint2 pcl;
      pcl.x = pkrtz(cst[0] - h2f((u16)pc.x), cst[1] - h2f((u16)(pc.x >> 16)));
      pcl.y = pkrtz(cst[2] - h2f((u16)pc.y), cst[3] - h2f((u16)(pc.y >> 16)));
      *(uint2*)&sh_cl[widx] = pcl;
    }

    is_cur = n_s; id_cur = n_d; ih_cur = n_h; ia_cur = n_a;
    __syncthreads();

    // ---- Y: finalize y[:, t] (wave 0) ----
    if (w == 0 && lane < 16) {
      const f4_t p0 = *(const f4_t*)&sh_red[lane * 8];
      const f4_t p1 = *(const f4_t*)&sh_red[lane * 8 + 4];
      float s = ((p0[0] + p0[1]) + (p0[2] + p0[3])) + ((p1[0] + p1[1]) + (p1[2] + p1[3]));
      out[(blockIdx.x * 16 + lane) * 200 + t] = sigm(s);
    }
  }
}

// ---------------- launcher ----------------

extern "C" void kernel_launch(void* const* d_in, const int* in_sizes, int n_in,
                              void* d_out, int out_size, void* d_ws, size_t ws_size,
                              hipStream_t stream) {
  const int* skill  = (const int*)d_in[0];
  const int* answer = (const int*)d_in[1];
  const int* diff   = (const int*)d_in[2];
  const int* hints  = (const int*)d_in[3];
  const float* skill_emb  = (const float*)d_in[5];
  const float* answer_emb = (const float*)d_in[6];
  const float* diff_emb   = (const float*)d_in[7];
  const float* hints_emb  = (const float*)d_in[8];
  const float* Wq2 = (const float*)d_in[10];
  const float* Wk2 = (const float*)d_in[11];
  const float* Wv2 = (const float*)d_in[12];
  const float* Wq3 = (const float*)d_in[13];
  const float* Wk3 = (const float*)d_in[14];
  const float* Wv3 = (const float*)d_in[15];
  const float* fc_W  = (const float*)d_in[16];
  const float* fc_b  = (const float*)d_in[17];
  const float* fc2_W = (const float*)d_in[18];
  const float* fc2_b = (const float*)d_in[19];
  const float* f11_W = (const float*)d_in[20];
  const float* f11_b = (const float*)d_in[21];
  const float* f12_W = (const float*)d_in[22];
  const float* f12_b = (const float*)d_in[23];
  const float* f21_W = (const float*)d_in[24];
  const float* f21_b = (const float*)d_in[25];
  const float* f22_W = (const float*)d_in[26];
  const float* f22_b = (const float*)d_in[27];

  float* ws = (float*)d_ws;
  float* A2 = ws + 0;          // 128x128
  float* A3 = ws + 16384;
  float* B2 = ws + 32768;
  float* B3 = ws + 49152;
  float* WB = ws + 65536;      // 256x384
  float* BB = ws + 163840;     // 384
  float* SKt = ws + 164224;    // 1002x384
  float* DFt = ws + 548992;    // 102x384
  float* TV2 = ws + 588160;    // 12x128
  float* TV3 = ws + 589696;    // 3x128
  u16* WHI = (u16*)((char*)d_ws + 2360320);  // 256 KB
  u16* WLO = (u16*)((char*)d_ws + 2622464);  // 256 KB
  float* outp = (float*)d_out;

  k_gemm128<<<16, 256, 0, stream>>>(fc2_W,         Wq2, B2);
  k_gemm128<<<16, 256, 0, stream>>>(fc2_W,         Wk3, B3);
  k_gemm128<<<16, 256, 0, stream>>>(fc2_W + 16384, Wq2, A2);
  k_gemm128<<<16, 256, 0, stream>>>(fc2_W + 16384, Wk3, A3);
  k_wbig<<<96, 256, 0, stream>>>(fc_W, B2, B3, WB);
  k_bbig<<<2, 256, 0, stream>>>(fc_b, fc2_b, B2, B3, Wq2, Wk3, BB);
  k_skdf<<<dim3(376, 2), 256, 0, stream>>>(skill_emb, diff_emb, WB, BB, SKt, DFt);
  k_tv<<<2, 256, 0, stream>>>(hints_emb, Wv2, answer_emb, Wv3, TV2, TV3);
  P8 s;
  s.p[0] = A2; s.p[1] = A3; s.p[2] = Wq3; s.p[3] = Wk2;
  s.p[4] = f11_W; s.p[5] = f12_W; s.p[6] = f21_W; s.p[7] = f22_W;
  k_pack<<<128, 256, 0, stream>>>(s, WHI, WLO);
  k_main<<<32, 512, 0, stream>>>(skill, answer, diff, hints, SKt, DFt, TV2, TV3,
                                 WHI, WLO, f11_b, f12_b, f21_b, f22_b, outp);
}

// Round 18
// 1209.962 us; speedup vs baseline: 1.4957x; 1.4957x over previous
//
#include <hip/hip_runtime.h>
#include <stdint.h>

typedef unsigned short u16;
typedef unsigned char u8;
typedef unsigned int u32;
typedef unsigned long long u64;

using h8f  = __attribute__((ext_vector_type(8))) _Float16;  // 8 f16 (one MFMA frag)
using f4_t = __attribute__((ext_vector_type(4))) float;
using l2_t = __attribute__((ext_vector_type(2))) long;      // 16B (two fp8 frags)

#define MFMAH(a,b,c)  __builtin_amdgcn_mfma_f32_16x16x32_f16((a),(b),(c),0,0,0)
#define MFMAF8(a,b,c) __builtin_amdgcn_mfma_f32_16x16x32_fp8_fp8((a),(b),(c),0,0,0)

#define LO_SCALE 4096.0f
#define LO_INV   0.000244140625f   // 1/4096

__device__ __forceinline__ float sigm(float x) {
  return __builtin_amdgcn_rcpf(1.f + __expf(-x));
}
__device__ __forceinline__ float tanh_f(float x) {
  x = fminf(30.f, fmaxf(-30.f, x));
  float e = __expf(-2.f * x);
  return (1.f - e) * __builtin_amdgcn_rcpf(1.f + e);
}
__device__ __forceinline__ u16 f2h_bits(float f) {   // RNE f32->f16 bits
  _Float16 h = (_Float16)f;
  union { _Float16 h; u16 u; } v; v.h = h; return v.u;
}
__device__ __forceinline__ float h2f(u16 u) {
  union { _Float16 h; u16 u; } v; v.u = u; return (float)v.h;
}
// v_cvt_pkrtz_f16_f32: 2 f32 -> 2 f16 (RTZ; paired with exact lo channel)
__device__ __forceinline__ u32 pkrtz(float a, float b) {
  union { __attribute__((ext_vector_type(2))) __fp16 h; u32 u; } v;
  v.h = __builtin_amdgcn_cvt_pkrtz(a, b);
  return v.u;
}
// pack 4 f32 -> 1 u32 of fp8 e4m3
__device__ __forceinline__ u32 pk4f8(float a, float b, float c, float d) {
  u32 r = 0;
  r = __builtin_amdgcn_cvt_pk_fp8_f32(a, b, (int)r, false);
  r = __builtin_amdgcn_cvt_pk_fp8_f32(c, d, (int)r, true);
  return r;
}

// ---------------- prep kernels ----------------

__global__ void k_gemm128(const float* __restrict__ A, const float* __restrict__ B,
                          float* __restrict__ C) {
  int g = blockIdx.x * 256 + threadIdx.x;
  int row = g >> 5;
  int c0 = (g & 31) << 2;
  f4_t acc = {0.f, 0.f, 0.f, 0.f};
  for (int k = 0; k < 128; ++k) {
    float a = A[row * 128 + k];
    acc += a * *(const f4_t*)&B[k * 128 + c0];
  }
  *(f4_t*)&C[row * 128 + c0] = acc;
}

__global__ void k_wbig(const float* __restrict__ fc_W, const float* __restrict__ B2,
                       const float* __restrict__ B3, float* __restrict__ WB) {
  int g = blockIdx.x * 256 + threadIdx.x;
  int row = g / 96;
  int j0 = (g % 96) * 4;
  if (j0 < 128) {
    *(f4_t*)&WB[row * 384 + j0] = *(const f4_t*)&fc_W[row * 128 + j0];
  } else {
    const float* Bm = (j0 < 256) ? B2 : B3;
    int jj = j0 & 127;
    f4_t acc = {0.f, 0.f, 0.f, 0.f};
    for (int n = 0; n < 128; ++n)
      acc += fc_W[row * 128 + n] * *(const f4_t*)&Bm[n * 128 + jj];
    *(f4_t*)&WB[row * 384 + j0] = acc;
  }
}

__global__ void k_bbig(const float* __restrict__ fc_b, const float* __restrict__ fc2_b,
                       const float* __restrict__ B2, const float* __restrict__ B3,
                       const float* __restrict__ Wq2, const float* __restrict__ Wk3,
                       float* __restrict__ bb) {
  int j = blockIdx.x * 256 + threadIdx.x;
  if (j >= 384) return;
  if (j < 128) { bb[j] = fc_b[j]; return; }
  const float* Bm = (j < 256) ? B2 : B3;
  const float* Wm = (j < 256) ? Wq2 : Wk3;
  int jj = j & 127;
  float acc = 0.f;
  for (int n = 0; n < 128; ++n)
    acc += fc_b[n] * Bm[n * 128 + jj] + fc2_b[n] * Wm[n * 128 + jj];
  bb[j] = acc;
}

__global__ void k_skdf(const float* __restrict__ skill_emb, const float* __restrict__ diff_emb,
                       const float* __restrict__ WB, const float* __restrict__ bb,
                       float* __restrict__ SK, float* __restrict__ DF) {
  int g = blockIdx.x * 256 + threadIdx.x;
  int row = g / 96, j0 = (g % 96) * 4;
  if (blockIdx.y == 0) {
    if (row >= 1002) return;
    f4_t acc = {0.f, 0.f, 0.f, 0.f};
    for (int d = 0; d < 128; ++d)
      acc += skill_emb[row * 128 + d] * *(const f4_t*)&WB[d * 384 + j0];
    *(f4_t*)&SK[row * 384 + j0] = acc;
  } else {
    if (row >= 102) return;
    f4_t acc = *(const f4_t*)&bb[j0];
    for (int d = 0; d < 128; ++d)
      acc += diff_emb[row * 128 + d] * *(const f4_t*)&WB[(128 + d) * 384 + j0];
    *(f4_t*)&DF[row * 384 + j0] = acc;
  }
}

__global__ void k_tv(const float* __restrict__ hints_emb, const float* __restrict__ Wv2,
                     const float* __restrict__ answer_emb, const float* __restrict__ Wv3,
                     float* __restrict__ Tv2, float* __restrict__ Tv3) {
  int g = blockIdx.x * 256 + threadIdx.x;
  if (g < 384) {
    int i = g >> 5, j0 = (g & 31) << 2;
    f4_t acc = {0.f, 0.f, 0.f, 0.f};
    for (int d = 0; d < 128; ++d)
      acc += hints_emb[i * 128 + d] * *(const f4_t*)&Wv2[d * 128 + j0];
    *(f4_t*)&Tv2[i * 128 + j0] = acc;
  } else if (g < 480) {
    int g2 = g - 384;
    int i = g2 >> 5, j0 = (g2 & 31) << 2;
    f4_t acc = {0.f, 0.f, 0.f, 0.f};
    for (int d = 0; d < 128; ++d)
      acc += answer_emb[i * 128 + d] * *(const f4_t*)&Wv3[d * 128 + j0];
    *(f4_t*)&Tv3[i * 128 + j0] = acc;
  }
}

// Pack in-loop weights. 8-wave layout: wave w (0..7) owns cols [16w,16w+16).
// frag flat index f = ((m*4+kk)*8 + w)*64 + lane
// whi: f16 hi (8 u16/frag). wl8: fp8 e4m3 of ((w - f16(w)) * 4096) (8 B/frag).
struct P8 { const float* p[8]; };
__global__ void k_pack(P8 s, u16* __restrict__ whi, u8* __restrict__ wl8) {
  int g = blockIdx.x * 256 + threadIdx.x;   // 128*256 = 32768
  bool lo = (g >= 16384);
  int gg = g & 16383;
  int m = gg >> 11;
  int r = gg & 2047;
  int kk = r >> 9, w = (r >> 6) & 7, l = r & 63;
  const float* src = s.p[m];
  int col = w * 16 + (l & 15);
  int kbase = kk * 32 + ((l >> 4) << 3);
  if (!lo) {
    u16 o[8];
    #pragma unroll
    for (int e = 0; e < 8; ++e) o[e] = f2h_bits(src[(kbase + e) * 128 + col]);
    uint4 u;
    u.x = o[0] | ((u32)o[1] << 16); u.y = o[2] | ((u32)o[3] << 16);
    u.z = o[4] | ((u32)o[5] << 16); u.w = o[6] | ((u32)o[7] << 16);
    *(uint4*)(whi + gg * 8) = u;
  } else {
    float lv[8];
    #pragma unroll
    for (int e = 0; e < 8; ++e) {
      float v = src[(kbase + e) * 128 + col];
      lv[e] = (v - (float)((_Float16)v)) * LO_SCALE;
    }
    uint2 u;
    u.x = pk4f8(lv[0], lv[1], lv[2], lv[3]);
    u.y = pk4f8(lv[4], lv[5], lv[6], lv[7]);
    *(uint2*)(wl8 + (size_t)gg * 8) = u;
  }
}

// ---------------- main recurrent kernel ----------------
// R14 structure (empirical optimum of this design space): 32 blocks x 512
// threads (8 waves, 2 waves/SIMD). Block owns 16 batch rows; wave w owns
// feature cols [16w,16w+16). WH f16-hi register-resident; WL fp8 (res*4096)
// streamed from L2 each stage (b64, 128KB footprint). Acts f16 hi+lo in LDS
// (eff 2^-22) + interleaved fp8 copies feeding the lo-weight MFMAs.
// Biases hoisted to registers (loop-invariant).

#define RSTRIDE 136   // u16 stride (272 B)
#define RS8 272       // byte stride for interleaved fp8 arrays

__launch_bounds__(512, 2)
__global__ void k_main(const int* __restrict__ skill, const int* __restrict__ answer,
                       const int* __restrict__ diff, const int* __restrict__ hints,
                       const float* __restrict__ SK, const float* __restrict__ DF,
                       const float* __restrict__ Tv2, const float* __restrict__ Tv3,
                       const u16* __restrict__ whi, const u8* __restrict__ wl8,
                       const float* __restrict__ b11p, const float* __restrict__ b12p,
                       const float* __restrict__ b21p, const float* __restrict__ b22p,
                       float* __restrict__ out) {
  __shared__ u16 sh_h[16 * RSTRIDE], sh_hl[16 * RSTRIDE];
  __shared__ u16 sh_c[16 * RSTRIDE], sh_cl[16 * RSTRIDE];
  __shared__ u16 sh_o[16 * RSTRIDE], sh_ol[16 * RSTRIDE];
  __shared__ u16 sh_o3[16 * RSTRIDE], sh_o3l[16 * RSTRIDE];
  __shared__ u8 sh_hc8[16 * RS8];   // [h8(8B) | c8(8B)] per 8-feat block
  __shared__ u8 sh_oo8[16 * RS8];   // [o8(8B) | o38(8B)] per 8-feat block
  __shared__ float sh_red[128];

  const int tid = threadIdx.x;
  const int w = tid >> 6, lane = tid & 63;
  const int row = lane & 15;
  const int fgrp = lane >> 4;
  const int f0 = w * 16 + fgrp * 4;
  const int row_g = blockIdx.x * 16 + row;
  const int r200 = row_g * 200;

  // -------- persistent weights (hi f16 only; lo fp8 streamed) --------
  h8f WH[8][4];
  {
    #pragma unroll
    for (int m = 0; m < 8; ++m)
      #pragma unroll
      for (int kk = 0; kk < 4; ++kk)
        WH[m][kk] = *(const h8f*)&whi[(size_t)(((m * 4 + kk) * 8 + w) * 64 + lane) * 8];
  }
  const u8* wlp = wl8 + (size_t)(w * 64 + lane) * 8;   // + (m*4+kk)*512*8

  // loop-invariant biases (hoisted)
  const f4_t b11 = *(const f4_t*)&b11p[f0];
  const f4_t b12 = *(const f4_t*)&b12p[f0];
  const f4_t b21 = *(const f4_t*)&b21p[f0];
  const f4_t b22 = *(const f4_t*)&b22p[f0];

  // LDS init (h,c hi/lo and fp8 copies = 0)
  for (int i = tid; i < 16 * RSTRIDE / 2; i += 512) {
    ((u32*)sh_h)[i] = 0u; ((u32*)sh_c)[i] = 0u;
    ((u32*)sh_hl)[i] = 0u; ((u32*)sh_cl)[i] = 0u;
  }
  for (int i = tid; i < 16 * RS8 / 4; i += 512) ((u32*)sh_hc8)[i] = 0u;
  if (tid < 16) out[(blockIdx.x * 16 + tid) * 200 + 199] = 0.f;  // y[:,199]=0

  f4_t cst = {0.f, 0.f, 0.f, 0.f};

  int is_cur = skill[r200], id_cur = diff[r200];
  int ih_cur = hints[r200], ia_cur = answer[r200];

  const float inv = 0.088388347648318447f;  // 1/sqrt(128)
  const int rbase = row * RSTRIDE;
  const int widx = rbase + f0;
  int roff[4], boff[4];
  #pragma unroll
  for (int kk = 0; kk < 4; ++kk) {
    roff[kk] = rbase + kk * 32 + fgrp * 8;
    boff[kk] = row * RS8 + (kk * 4 + fgrp) * 16;
  }
  // interleaved fp8 write offset: u32 slot j = w*4+fgrp; block j>>1, half j&1
  const int w8 = row * RS8 + (w * 2 + (fgrp >> 1)) * 16 + (fgrp & 1) * 4;

  __syncthreads();

  for (int t = 0; t < 199; ++t) {
    // ---- S1 top: stream stage-1 WL (L2) + global table loads ----
    long wls[4][4];
    #pragma unroll
    for (int m = 0; m < 4; ++m)
      #pragma unroll
      for (int kk = 0; kk < 4; ++kk)
        wls[m][kk] = *(const long*)(wlp + (size_t)((m * 4 + kk) * 512) * 8);
    f4_t v2  = *(const f4_t*)&Tv2[ih_cur * 128 + f0];
    f4_t v3  = *(const f4_t*)&Tv3[ia_cur * 128 + f0];
    f4_t q2b = *(const f4_t*)&SK[is_cur * 384 + 128 + f0]
             + *(const f4_t*)&DF[id_cur * 384 + 128 + f0];
    f4_t q3b = *(const f4_t*)&SK[is_cur * 384 + 256 + f0]
             + *(const f4_t*)&DF[id_cur * 384 + 256 + f0];
    int n_s = skill[r200 + t + 1];
    int n_d = diff[r200 + t + 1];
    int n_h = hints[r200 + t + 1];
    int n_a = answer[r200 + t + 1];

    // ---- stage 1 f16 MFMAs ----
    f4_t q2 = {0.f,0.f,0.f,0.f}, q3 = {0.f,0.f,0.f,0.f};
    f4_t k3 = {0.f,0.f,0.f,0.f}, k2 = {0.f,0.f,0.f,0.f};
    #pragma unroll
    for (int kk = 0; kk < 4; ++kk) {
      h8f hh = *(const h8f*)&sh_h[roff[kk]];
      h8f hl = *(const h8f*)&sh_hl[roff[kk]];
      h8f ch = *(const h8f*)&sh_c[roff[kk]];
      h8f cl = *(const h8f*)&sh_cl[roff[kk]];
      q2 = MFMAH(WH[0][kk], hh, q2); q2 = MFMAH(WH[0][kk], hl, q2);
      q3 = MFMAH(WH[1][kk], hh, q3); q3 = MFMAH(WH[1][kk], hl, q3);
      k3 = MFMAH(WH[2][kk], hh, k3); k3 = MFMAH(WH[2][kk], hl, k3);
      k2 = MFMAH(WH[3][kk], ch, k2); k2 = MFMAH(WH[3][kk], cl, k2);
    }
    // ---- stage 1 fp8 lo MFMAs (streamed WL now arrived) ----
    f4_t lq2 = {0.f,0.f,0.f,0.f}, lq3 = {0.f,0.f,0.f,0.f};
    f4_t lk3 = {0.f,0.f,0.f,0.f}, lk2 = {0.f,0.f,0.f,0.f};
    #pragma unroll
    for (int kk = 0; kk < 4; ++kk) {
      l2_t hc = *(const l2_t*)&sh_hc8[boff[kk]];
      long h8 = hc[0], c8 = hc[1];
      lq2 = MFMAF8(wls[0][kk], h8, lq2);
      lq3 = MFMAF8(wls[1][kk], h8, lq3);
      lk3 = MFMAF8(wls[2][kk], h8, lk3);
      lk2 = MFMAF8(wls[3][kk], c8, lk2);
    }

    // ---- E1: gates + write o/o3 (f16 hi+lo + interleaved fp8 copy) ----
    {
      float ov[4], o3v[4];
      #pragma unroll
      for (int r = 0; r < 4; ++r) {
        float q2v = (q2[r] + lq2[r] * LO_INV) + q2b[r];
        float q3v = (q3[r] + lq3[r] * LO_INV) + q3b[r];
        float k2v = k2[r] + lk2[r] * LO_INV;
        float k3v = k3[r] + lk3[r] * LO_INV;
        ov[r]  = v2[r] * sigm(q2v * k2v * inv);
        o3v[r] = v3[r] * sigm(q3v * k3v * inv);
      }
      uint2 ph; ph.x = pkrtz(ov[0], ov[1]); ph.y = pkrtz(ov[2], ov[3]);
      *(uint2*)&sh_o[widx] = ph;
      uint2 pl;
      pl.x = pkrtz(ov[0] - h2f((u16)ph.x), ov[1] - h2f((u16)(ph.x >> 16)));
      pl.y = pkrtz(ov[2] - h2f((u16)ph.y), ov[3] - h2f((u16)(ph.y >> 16)));
      *(uint2*)&sh_ol[widx] = pl;
      uint2 p3; p3.x = pkrtz(o3v[0], o3v[1]); p3.y = pkrtz(o3v[2], o3v[3]);
      *(uint2*)&sh_o3[widx] = p3;
      uint2 p3l;
      p3l.x = pkrtz(o3v[0] - h2f((u16)p3.x), o3v[1] - h2f((u16)(p3.x >> 16)));
      p3l.y = pkrtz(o3v[2] - h2f((u16)p3.y), o3v[3] - h2f((u16)(p3.y >> 16)));
      *(uint2*)&sh_o3l[widx] = p3l;
      *(u32*)&sh_oo8[w8]     = pk4f8(ov[0], ov[1], ov[2], ov[3]);
      *(u32*)&sh_oo8[w8 + 8] = pk4f8(o3v[0], o3v[1], o3v[2], o3v[3]);
    }
    __syncthreads();

    // ---- S2 top: stream stage-2 WL + xn tables ----
    long wls2[4][4];
    #pragma unroll
    for (int m = 0; m < 4; ++m)
      #pragma unroll
      for (int kk = 0; kk < 4; ++kk)
        wls2[m][kk] = *(const long*)(wlp + (size_t)(((m + 4) * 4 + kk) * 512) * 8);
    f4_t xn = *(const f4_t*)&SK[n_s * 384 + f0] + *(const f4_t*)&DF[n_d * 384 + f0];

    // ---- stage 2 f16 MFMAs ----
    f4_t a11 = {0.f,0.f,0.f,0.f}, a12 = {0.f,0.f,0.f,0.f};
    f4_t a21 = {0.f,0.f,0.f,0.f}, a22 = {0.f,0.f,0.f,0.f};
    #pragma unroll
    for (int kk = 0; kk < 4; ++kk) {
      h8f of   = *(const h8f*)&sh_o[roff[kk]];
      h8f olf  = *(const h8f*)&sh_ol[roff[kk]];
      h8f o3f  = *(const h8f*)&sh_o3[roff[kk]];
      h8f o3lf = *(const h8f*)&sh_o3l[roff[kk]];
      a11 = MFMAH(WH[4][kk], of, a11);  a11 = MFMAH(WH[4][kk], olf, a11);
      a12 = MFMAH(WH[5][kk], of, a12);  a12 = MFMAH(WH[5][kk], olf, a12);
      a21 = MFMAH(WH[6][kk], o3f, a21); a21 = MFMAH(WH[6][kk], o3lf, a21);
      a22 = MFMAH(WH[7][kk], o3f, a22); a22 = MFMAH(WH[7][kk], o3lf, a22);
    }
    // ---- stage 2 fp8 lo MFMAs ----
    f4_t l11 = {0.f,0.f,0.f,0.f}, l12 = {0.f,0.f,0.f,0.f};
    f4_t l21 = {0.f,0.f,0.f,0.f}, l22 = {0.f,0.f,0.f,0.f};
    #pragma unroll
    for (int kk = 0; kk < 4; ++kk) {
      l2_t oo = *(const l2_t*)&sh_oo8[boff[kk]];
      long o8 = oo[0], o38 = oo[1];
      l11 = MFMAF8(wls2[0][kk], o8, l11);
      l12 = MFMAF8(wls2[1][kk], o8, l12);
      l21 = MFMAF8(wls2[2][kk], o38, l21);
      l22 = MFMAF8(wls2[3][kk], o38, l22);
    }

    // ---- E2: state update + y partial + write h,c (f16 hi+lo + fp8) ----
    float part = 0.f;
    f4_t hv;
    #pragma unroll
    for (int r = 0; r < 4; ++r) {
      float v11 = (a11[r] + l11[r] * LO_INV) + b11[r];
      float v12 = (a12[r] + l12[r] * LO_INV) + b12[r];
      float v21 = (a21[r] + l21[r] * LO_INV) + b21[r];
      float v22 = (a22[r] + l22[r] * LO_INV) + b22[r];
      float g = tanh_f(v11) * sigm(v12);
      cst[r] += g;
      float hh = tanh_f(v21) * sigm(v22) + cst[r];
      hv[r] = hh;
      part += xn[r] * hh;
    }
    part += __shfl_xor(part, 16);
    part += __shfl_xor(part, 32);
    if (lane < 16) sh_red[lane * 8 + w] = part;

    {
      uint2 ph; ph.x = pkrtz(hv[0], hv[1]); ph.y = pkrtz(hv[2], hv[3]);
      *(uint2*)&sh_h[widx] = ph;
      uint2 pl;
      pl.x = pkrtz(hv[0] - h2f((u16)ph.x), hv[1] - h2f((u16)(ph.x >> 16)));
      pl.y = pkrtz(hv[2] - h2f((u16)ph.y), hv[3] - h2f((u16)(ph.y >> 16)));
      *(uint2*)&sh_hl[widx] = pl;
      uint2 pc; pc.x = pkrtz(cst[0], cst[1]); pc.y = pkrtz(cst[2], cst[3]);
      *(uint2*)&sh_c[widx] = pc;
      uint2 pcl;
      pcl.x = pkrtz(cst[0] - h2f((u16)pc.x), cst[1] - h2f((u16)(pc.x >> 16)));
      pcl.y = pkrtz(cst[2] - h2f((u16)pc.y), cst[3] - h2f((u16)(pc.y >> 16)));
      *(uint2*)&sh_cl[widx] = pcl;
      *(u32*)&sh_hc8[w8]     = pk4f8(hv[0], hv[1], hv[2], hv[3]);
      *(u32*)&sh_hc8[w8 + 8] = pk4f8(cst[0], cst[1], cst[2], cst[3]);
    }

    is_cur = n_s; id_cur = n_d; ih_cur = n_h; ia_cur = n_a;
    __syncthreads();

    // ---- Y: finalize y[:, t] (wave 0) ----
    if (w == 0 && lane < 16) {
      const f4_t p0 = *(const f4_t*)&sh_red[lane * 8];
      const f4_t p1 = *(const f4_t*)&sh_red[lane * 8 + 4];
      float s = ((p0[0] + p0[1]) + (p0[2] + p0[3])) + ((p1[0] + p1[1]) + (p1[2] + p1[3]));
      out[(blockIdx.x * 16 + lane) * 200 + t] = sigm(s);
    }
  }
}

// ---------------- launcher ----------------

extern "C" void kernel_launch(void* const* d_in, const int* in_sizes, int n_in,
                              void* d_out, int out_size, void* d_ws, size_t ws_size,
                              hipStream_t stream) {
  const int* skill  = (const int*)d_in[0];
  const int* answer = (const int*)d_in[1];
  const int* diff   = (const int*)d_in[2];
  const int* hints  = (const int*)d_in[3];
  const float* skill_emb  = (const float*)d_in[5];
  const float* answer_emb = (const float*)d_in[6];
  const float* diff_emb   = (const float*)d_in[7];
  const float* hints_emb  = (const float*)d_in[8];
  const float* Wq2 = (const float*)d_in[10];
  const float* Wk2 = (const float*)d_in[11];
  const float* Wv2 = (const float*)d_in[12];
  const float* Wq3 = (const float*)d_in[13];
  const float* Wk3 = (const float*)d_in[14];
  const float* Wv3 = (const float*)d_in[15];
  const float* fc_W  = (const float*)d_in[16];
  const float* fc_b  = (const float*)d_in[17];
  const float* fc2_W = (const float*)d_in[18];
  const float* fc2_b = (const float*)d_in[19];
  const float* f11_W = (const float*)d_in[20];
  const float* f11_b = (const float*)d_in[21];
  const float* f12_W = (const float*)d_in[22];
  const float* f12_b = (const float*)d_in[23];
  const float* f21_W = (const float*)d_in[24];
  const float* f21_b = (const float*)d_in[25];
  const float* f22_W = (const float*)d_in[26];
  const float* f22_b = (const float*)d_in[27];

  float* ws = (float*)d_ws;
  float* A2 = ws + 0;          // 128x128
  float* A3 = ws + 16384;
  float* B2 = ws + 32768;
  float* B3 = ws + 49152;
  float* WB = ws + 65536;      // 256x384
  float* BB = ws + 163840;     // 384
  float* SKt = ws + 164224;    // 1002x384
  float* DFt = ws + 548992;    // 102x384
  float* TV2 = ws + 588160;    // 12x128
  float* TV3 = ws + 589696;    // 3x128
  u16* WHI = (u16*)((char*)d_ws + 2360320);  // 256 KB
  u8* WL8 = (u8*)d_ws + 2622464;             // 128 KB
  float* outp = (float*)d_out;

  k_gemm128<<<16, 256, 0, stream>>>(fc2_W,         Wq2, B2);
  k_gemm128<<<16, 256, 0, stream>>>(fc2_W,         Wk3, B3);
  k_gemm128<<<16, 256, 0, stream>>>(fc2_W + 16384, Wq2, A2);
  k_gemm128<<<16, 256, 0, stream>>>(fc2_W + 16384, Wk3, A3);
  k_wbig<<<96, 256, 0, stream>>>(fc_W, B2, B3, WB);
  k_bbig<<<2, 256, 0, stream>>>(fc_b, fc2_b, B2, B3, Wq2, Wk3, BB);
  k_skdf<<<dim3(376, 2), 256, 0, stream>>>(skill_emb, diff_emb, WB, BB, SKt, DFt);
  k_tv<<<2, 256, 0, stream>>>(hints_emb, Wv2, answer_emb, Wv3, TV2, TV3);
  P8 s;
  s.p[0] = A2; s.p[1] = A3; s.p[2] = Wq3; s.p[3] = Wk2;
  s.p[4] = f11_W; s.p[5] = f12_W; s.p[6] = f21_W; s.p[7] = f22_W;
  k_pack<<<128, 256, 0, stream>>>(s, WHI, WL8);
  k_main<<<32, 512, 0, stream>>>(skill, answer, diff, hints, SKt, DFt, TV2, TV3,
                                 WHI, WL8, f11_b, f12_b, f21_b, f22_b, outp);
}